// Round 1
// baseline (365.567 us; speedup 1.0000x reference)
//
#include <hip/hip_runtime.h>

// GraphSAGE forward, 3 layers.
// Layer: agg = mean_k h[adj[k][n]]; hcat = [h | agg]; out = hcat @ W (+ReLU)
// N=50000, K=16, dims: 128 ->(256x128) 128 ->(256x128) 128 ->(256x64) 64

#define NODES_PER_BLOCK 32
#define KNBR 16

template<int FI, int FO, bool RELU>
__global__ __launch_bounds__(256)
void sage_layer(const float* __restrict__ h,
                const int* __restrict__ adj,
                const float* __restrict__ W,
                float* __restrict__ out,
                int N)
{
    // hcat[node][0..FI-1] = self, hcat[node][FI..2FI-1] = mean of neighbors
    __shared__ float hcat[NODES_PER_BLOCK][2 * FI];

    const int tid  = threadIdx.x;
    const int base = blockIdx.x * NODES_PER_BLOCK;

    // ---------- phase 1: gather + mean into LDS ----------
    {
        const int f       = tid & (FI - 1);      // feature index
        const int sub     = tid / FI;            // node subgroup
        const int ngroups = 256 / FI;            // 2 for FI=128
        for (int ln = sub; ln < NODES_PER_BLOCK; ln += ngroups) {
            const int n = base + ln;
            if (n < N) {
                const float self = h[(size_t)n * FI + f];
                float s = 0.f;
                #pragma unroll
                for (int k = 0; k < KNBR; ++k) {
                    const int idx = adj[(size_t)k * N + n];   // wave-uniform -> s_load
                    s += h[(size_t)idx * FI + f];
                }
                hcat[ln][f]      = self;
                hcat[ln][FI + f] = s * (1.0f / (float)KNBR);
            }
        }
    }
    __syncthreads();

    // ---------- phase 2: [NB x 2FI] @ [2FI x FO] ----------
    {
        const int j   = tid & (FO - 1);          // output column
        const int g   = tid / FO;                // node subgroup
        const int ng  = 256 / FO;                // 2 for FO=128, 4 for FO=64
        const int LPT = NODES_PER_BLOCK / (256 / FO);  // accumulators per thread

        float acc[NODES_PER_BLOCK];              // only LPT used (compile-time)
        #pragma unroll
        for (int l = 0; l < NODES_PER_BLOCK; ++l) acc[l] = 0.f;

        #pragma unroll 4
        for (int i = 0; i < 2 * FI; i += 4) {
            const float w0 = W[(size_t)(i + 0) * FO + j];
            const float w1 = W[(size_t)(i + 1) * FO + j];
            const float w2 = W[(size_t)(i + 2) * FO + j];
            const float w3 = W[(size_t)(i + 3) * FO + j];
            #pragma unroll
            for (int l = 0; l < NODES_PER_BLOCK; ++l) {
                if (l < LPT) {
                    const int ln = g + l * ng;
                    const float4 hv = *reinterpret_cast<const float4*>(&hcat[ln][i]);
                    float a = acc[l];
                    a = fmaf(hv.x, w0, a);
                    a = fmaf(hv.y, w1, a);
                    a = fmaf(hv.z, w2, a);
                    a = fmaf(hv.w, w3, a);
                    acc[l] = a;
                }
            }
        }

        #pragma unroll
        for (int l = 0; l < NODES_PER_BLOCK; ++l) {
            if (l < LPT) {
                const int ln = g + l * ng;
                const int n  = base + ln;
                if (n < N) {
                    float v = acc[l];
                    if (RELU) v = fmaxf(v, 0.f);
                    out[(size_t)n * FO + j] = v;
                }
            }
        }
    }
}

extern "C" void kernel_launch(void* const* d_in, const int* in_sizes, int n_in,
                              void* d_out, int out_size, void* d_ws, size_t ws_size,
                              hipStream_t stream) {
    const int N    = 50000;
    const int F    = 128;
    const int NCLS = 64;

    const float* x   = (const float*)d_in[0];
    const int*   adj = (const int*)  d_in[1];
    const float* W0  = (const float*)d_in[2];
    const float* W1  = (const float*)d_in[3];
    const float* W2  = (const float*)d_in[4];
    float* logits = (float*)d_out;

    float* h1 = (float*)d_ws;                    // [N,128] = 25.6 MB
    float* h2 = h1 + (size_t)N * F;              // [N,128] = 25.6 MB

    const int grid = (N + NODES_PER_BLOCK - 1) / NODES_PER_BLOCK;

    sage_layer<128, 128, true ><<<grid, 256, 0, stream>>>(x,  adj, W0, h1,     N);
    sage_layer<128, 128, true ><<<grid, 256, 0, stream>>>(h1, adj, W1, h2,     N);
    sage_layer<128, 64,  false><<<grid, 256, 0, stream>>>(h2, adj, W2, logits, N);
}

// Round 2
// 114.667 us; speedup vs baseline: 3.1881x; 3.1881x over previous
//
#include <hip/hip_runtime.h>

// GraphSAGE forward, 3 layers, bf16 storage + MFMA GEMM.
// Layer: agg = mean_k h[adj[k][n]]; hcat = [h | agg] (bf16 in LDS); out = hcat @ W
// N=50000, K=16, dims: 128 ->(256x128,relu) 128 ->(256x128,relu) 128 ->(256x64) 64

#define KNBR 16
#define MT   64     // nodes per block (M-tile)
#define LDA  272    // padded LDS row stride in bf16 elems (256 + 16) -> 544B = 8 banks mod 32

typedef __attribute__((ext_vector_type(8))) short short8;
typedef __attribute__((ext_vector_type(4))) float f32x4;

__device__ inline float bf2f(unsigned short u) {
    union { unsigned int i; float f; } c; c.i = ((unsigned int)u) << 16; return c.f;
}
__device__ inline unsigned short f2bf(float f) {
    union { float f; unsigned int i; } c; c.f = f;
    unsigned int u = c.i;
    u += 0x7FFFu + ((u >> 16) & 1u);   // RNE (finite data, no NaN handling needed)
    return (unsigned short)(u >> 16);
}

// ---------------- prep kernels ----------------

__global__ __launch_bounds__(256)
void cvt_x_kernel(const float* __restrict__ x, unsigned short* __restrict__ xb, int total4) {
    int i = blockIdx.x * 256 + threadIdx.x;
    if (i < total4) {
        float4 v = reinterpret_cast<const float4*>(x)[i];
        ushort4 o;
        o.x = f2bf(v.x); o.y = f2bf(v.y); o.z = f2bf(v.z); o.w = f2bf(v.w);
        reinterpret_cast<ushort4*>(xb)[i] = o;
    }
}

// Wt[j][k] = bf16(W[k][j]),  W: [256][FO], Wt: [FO][256]
__global__ __launch_bounds__(256)
void wt_kernel(const float* __restrict__ W, unsigned short* __restrict__ Wt, int FO) {
    int id = blockIdx.x * 256 + threadIdx.x;
    if (id < 256 * FO) {
        int j = id >> 8;
        int k = id & 255;
        Wt[id] = f2bf(W[k * FO + j]);
    }
}

// ---------------- layer kernel ----------------

template<int FO, bool RELU, bool OUTF32>
__global__ __launch_bounds__(256, 3)
void sage_layer(const unsigned short* __restrict__ h,   // [N][128] bf16
                const int* __restrict__ adj,            // [16][N]
                const unsigned short* __restrict__ Wt,  // [FO][256] bf16 (transposed W)
                void* __restrict__ outp,                // [N][FO] bf16 or f32
                int N)
{
    __shared__ unsigned short A[MT][LDA];   // hcat tile: [0..127]=self, [128..255]=agg
    __shared__ int idxs[MT][KNBR];

    const int tid  = threadIdx.x;
    const int base = blockIdx.x * MT;

    // ---- phase 0: neighbor indices -> LDS (coalesced over n) ----
    {
        const int nn = tid & 63;
        const int q  = tid >> 6;            // 0..3
        int n = base + nn; if (n >= N) n = N - 1;
        #pragma unroll
        for (int rep = 0; rep < 4; ++rep) {
            const int kk = rep * 4 + q;
            idxs[nn][kk] = adj[(size_t)kk * N + n];
        }
    }
    __syncthreads();

    // ---- phase 1: gather + mean (f32 accum) -> bf16 LDS tile ----
    {
        const int lane16 = tid & 15;
        const int grp    = tid >> 4;        // 0..15
        const int f0     = lane16 * 8;      // bf16 feature offset, 16B granules
        #pragma unroll
        for (int i = 0; i < 4; ++i) {
            const int ln = grp * 4 + i;
            int n = base + ln; if (n >= N) n = N - 1;
            // self row: bf16 passthrough, 16B
            const uint4 selfv = *reinterpret_cast<const uint4*>(&h[(size_t)n * 128 + f0]);
            *reinterpret_cast<uint4*>(&A[ln][f0]) = selfv;
            // neighbor mean
            float s[8];
            #pragma unroll
            for (int e = 0; e < 8; ++e) s[e] = 0.f;
            #pragma unroll
            for (int k = 0; k < KNBR; ++k) {
                const int id = idxs[ln][k];
                const uint4 v = *reinterpret_cast<const uint4*>(&h[(size_t)id * 128 + f0]);
                unsigned int w0 = v.x, w1 = v.y, w2 = v.z, w3 = v.w;
                s[0] += bf2f((unsigned short)(w0 & 0xFFFFu));
                s[1] += bf2f((unsigned short)(w0 >> 16));
                s[2] += bf2f((unsigned short)(w1 & 0xFFFFu));
                s[3] += bf2f((unsigned short)(w1 >> 16));
                s[4] += bf2f((unsigned short)(w2 & 0xFFFFu));
                s[5] += bf2f((unsigned short)(w2 >> 16));
                s[6] += bf2f((unsigned short)(w3 & 0xFFFFu));
                s[7] += bf2f((unsigned short)(w3 >> 16));
            }
            uint4 packed;
            packed.x = (unsigned int)f2bf(s[0] * 0.0625f) | ((unsigned int)f2bf(s[1] * 0.0625f) << 16);
            packed.y = (unsigned int)f2bf(s[2] * 0.0625f) | ((unsigned int)f2bf(s[3] * 0.0625f) << 16);
            packed.z = (unsigned int)f2bf(s[4] * 0.0625f) | ((unsigned int)f2bf(s[5] * 0.0625f) << 16);
            packed.w = (unsigned int)f2bf(s[6] * 0.0625f) | ((unsigned int)f2bf(s[7] * 0.0625f) << 16);
            *reinterpret_cast<uint4*>(&A[ln][128 + f0]) = packed;
        }
    }
    __syncthreads();

    // ---- phase 2: [64 x 256] @ [256 x FO] via mfma_f32_16x16x32_bf16 ----
    {
        constexpr int NCT = FO / 64;        // col-tiles per wave: 2 (FO=128) or 1 (FO=64)
        const int wv  = tid >> 6;           // wave 0..3
        const int l   = tid & 63;
        const int l15 = l & 15;
        const int kg  = l >> 4;             // 0..3 (k-group)

        f32x4 acc[4][NCT];
        #pragma unroll
        for (int rt = 0; rt < 4; ++rt)
            #pragma unroll
            for (int c = 0; c < NCT; ++c)
                acc[rt][c] = (f32x4){0.f, 0.f, 0.f, 0.f};

        // B fragment address base: lane's column row in Wt, k varies per step
        const unsigned short* wbase[NCT];
        #pragma unroll
        for (int c = 0; c < NCT; ++c) {
            const int col = (wv * NCT + c) * 16 + l15;
            wbase[c] = Wt + (size_t)col * 256 + kg * 8;
        }

        // prefetch B for ks=0
        short8 bcur[NCT], bnxt[NCT];
        #pragma unroll
        for (int c = 0; c < NCT; ++c)
            bcur[c] = *reinterpret_cast<const short8*>(wbase[c]);

        #pragma unroll
        for (int ks = 0; ks < 8; ++ks) {
            if (ks < 7) {
                #pragma unroll
                for (int c = 0; c < NCT; ++c)
                    bnxt[c] = *reinterpret_cast<const short8*>(wbase[c] + (ks + 1) * 32);
            }
            #pragma unroll
            for (int rt = 0; rt < 4; ++rt) {
                const short8 a = *reinterpret_cast<const short8*>(&A[rt * 16 + l15][ks * 32 + kg * 8]);
                #pragma unroll
                for (int c = 0; c < NCT; ++c)
                    acc[rt][c] = __builtin_amdgcn_mfma_f32_16x16x32_bf16(a, bcur[c], acc[rt][c], 0, 0, 0);
            }
            #pragma unroll
            for (int c = 0; c < NCT; ++c) bcur[c] = bnxt[c];
        }

        // epilogue: D col = lane&15 (within tile), row = 4*(lane>>4)+reg
        #pragma unroll
        for (int rt = 0; rt < 4; ++rt) {
            #pragma unroll
            for (int c = 0; c < NCT; ++c) {
                const int col = (wv * NCT + c) * 16 + l15;
                #pragma unroll
                for (int r = 0; r < 4; ++r) {
                    const int row = rt * 16 + kg * 4 + r;
                    const int n   = base + row;
                    if (n < N) {
                        float v = acc[rt][c][r];
                        if (RELU) v = fmaxf(v, 0.f);
                        if (OUTF32)
                            reinterpret_cast<float*>(outp)[(size_t)n * FO + col] = v;
                        else
                            reinterpret_cast<unsigned short*>(outp)[(size_t)n * FO + col] = f2bf(v);
                    }
                }
            }
        }
    }
}

extern "C" void kernel_launch(void* const* d_in, const int* in_sizes, int n_in,
                              void* d_out, int out_size, void* d_ws, size_t ws_size,
                              hipStream_t stream) {
    const int N = 50000;
    const int F = 128;

    const float* x   = (const float*)d_in[0];
    const int*   adj = (const int*)  d_in[1];
    const float* W0  = (const float*)d_in[2];
    const float* W1  = (const float*)d_in[3];
    const float* W2  = (const float*)d_in[4];
    float* logits = (float*)d_out;

    char* ws = (char*)d_ws;
    unsigned short* xb  = (unsigned short*)(ws);                     // [N][128] bf16 = 12.8 MB
    unsigned short* h1  = (unsigned short*)(ws + 12800000);          // 12.8 MB
    unsigned short* h2  = (unsigned short*)(ws + 25600000);          // 12.8 MB
    unsigned short* Wt0 = (unsigned short*)(ws + 38400000);          // 64 KB
    unsigned short* Wt1 = (unsigned short*)(ws + 38400000 + 65536);  // 64 KB
    unsigned short* Wt2 = (unsigned short*)(ws + 38400000 + 131072); // 32 KB

    // prep: x -> bf16, W -> bf16 transposed
    cvt_x_kernel<<<(N * F / 4 + 255) / 256, 256, 0, stream>>>(x, xb, N * F / 4);
    wt_kernel<<<128, 256, 0, stream>>>(W0, Wt0, 128);
    wt_kernel<<<128, 256, 0, stream>>>(W1, Wt1, 128);
    wt_kernel<<< 64, 256, 0, stream>>>(W2, Wt2, 64);

    const int grid = (N + MT - 1) / MT;   // 782

    sage_layer<128, true,  false><<<grid, 256, 0, stream>>>(xb, adj, Wt0, h1, N);
    sage_layer<128, true,  false><<<grid, 256, 0, stream>>>(h1, adj, Wt1, h2, N);
    sage_layer< 64, false, true ><<<grid, 256, 0, stream>>>(h2, adj, Wt2, logits, N);
}